// Round 2
// baseline (13898.373 us; speedup 1.0000x reference)
//
#include <hip/hip_runtime.h>

#define N_NODES 30000
#define N_EDGES 200000
#define DIM 768
#define N_REL 10
#define N_LAYERS 2
#define LN_EPS 1e-5f

#define BM 64
#define BN 64
#define BK 16

// ---------------- count edges per (dst, rel) segment (layer-invariant) ----------------
__global__ void count_kernel(const int* __restrict__ ei, const int* __restrict__ et,
                             int* __restrict__ cnt) {
    int e = blockIdx.x * blockDim.x + threadIdx.x;
    if (e >= N_EDGES) return;
    int dst = ei[N_EDGES + e];
    int r = et[e];
    atomicAdd(&cnt[dst * N_REL + r], 1);
}

// ---------------- scatter-add h[src] rows into sums[dst] for one relation ----------------
// one thread per (edge, float4-chunk); 192 chunks per edge; waves are edge-uniform (192 = 3*64)
__global__ void scatter_kernel(const float* __restrict__ h, const int* __restrict__ ei,
                               const int* __restrict__ et, float* __restrict__ sums, int rel) {
    int idx = blockIdx.x * blockDim.x + threadIdx.x;
    int e = idx / (DIM / 4);
    int c = idx % (DIM / 4);
    if (e >= N_EDGES) return;
    if (et[e] != rel) return;
    int src = ei[e];
    int dst = ei[N_EDGES + e];
    const float4 v = *reinterpret_cast<const float4*>(h + (size_t)src * DIM + c * 4);
    float* o = sums + (size_t)dst * DIM + c * 4;
    atomicAdd(o + 0, v.x);
    atomicAdd(o + 1, v.y);
    atomicAdd(o + 2, v.z);
    atomicAdd(o + 3, v.w);
}

// ---------------- C[N,D] += (rowscale(A)) @ B, f32 vector GEMM ----------------
// A: [N_NODES, DIM] row-major (sums or h); B: [DIM, DIM] row-major; C accumulate.
// If cnt != nullptr, row scale = 1/max(cnt[row*N_REL+rel],1), else 1.
__global__ void gemm_acc(const float* __restrict__ A, const float* __restrict__ B,
                         float* __restrict__ C, const int* __restrict__ cnt, int rel) {
    __shared__ float As[BK][BM + 4];
    __shared__ float Bs[BK][BN + 4];

    const int m0 = blockIdx.x * BM;
    const int n0 = blockIdx.y * BN;
    const int t = threadIdx.x;      // 0..255
    const int tx = t & 15;
    const int ty = t >> 4;

    // A-load mapping: 4 threads per row, each 1 float4 of k
    const int am = t >> 2;          // 0..63 (row within tile)
    const int ak = (t & 3) * 4;     // k offset within tile
    const int arow = m0 + am;
    float scale = 1.0f;
    if (cnt != nullptr && arow < N_NODES) {
        int c = cnt[arow * N_REL + rel];
        scale = 1.0f / (float)(c > 1 ? c : 1);
    }
    // B-load mapping: 16 threads per row, each 1 float4 of n
    const int bk = ty;              // 0..15
    const int bn = tx * 4;          // 0..60

    float acc[4][4] = {};

    for (int k0 = 0; k0 < DIM; k0 += BK) {
        float4 av = make_float4(0.f, 0.f, 0.f, 0.f);
        if (arow < N_NODES)
            av = *reinterpret_cast<const float4*>(A + (size_t)arow * DIM + k0 + ak);
        const float4 bv = *reinterpret_cast<const float4*>(B + (size_t)(k0 + bk) * DIM + n0 + bn);

        __syncthreads();  // previous iteration's reads done
        As[ak + 0][am] = av.x * scale;
        As[ak + 1][am] = av.y * scale;
        As[ak + 2][am] = av.z * scale;
        As[ak + 3][am] = av.w * scale;
        *reinterpret_cast<float4*>(&Bs[bk][bn]) = bv;
        __syncthreads();

#pragma unroll
        for (int k = 0; k < BK; ++k) {
            const float4 a = *reinterpret_cast<const float4*>(&As[k][ty * 4]);
            const float4 b = *reinterpret_cast<const float4*>(&Bs[k][tx * 4]);
            const float aa[4] = {a.x, a.y, a.z, a.w};
            const float bb[4] = {b.x, b.y, b.z, b.w};
#pragma unroll
            for (int i = 0; i < 4; ++i)
#pragma unroll
                for (int j = 0; j < 4; ++j)
                    acc[i][j] = fmaf(aa[i], bb[j], acc[i][j]);
        }
    }

#pragma unroll
    for (int i = 0; i < 4; ++i) {
        const int rr = m0 + ty * 4 + i;
        if (rr >= N_NODES) continue;
        float* cp = C + (size_t)rr * DIM + n0 + tx * 4;
        float4 cv = *reinterpret_cast<float4*>(cp);
        cv.x += acc[i][0];
        cv.y += acc[i][1];
        cv.z += acc[i][2];
        cv.w += acc[i][3];
        *reinterpret_cast<float4*>(cp) = cv;
    }
}

// ---------------- bias + LayerNorm + optional residual + optional relu ----------------
__device__ __forceinline__ float block_reduce_sum(float v, float* sm) {
#pragma unroll
    for (int o = 32; o > 0; o >>= 1) v += __shfl_down(v, o, 64);
    const int wid = threadIdx.x >> 6;
    const int lane = threadIdx.x & 63;
    __syncthreads();  // safe reuse of sm across calls
    if (lane == 0) sm[wid] = v;
    __syncthreads();
    return sm[0] + sm[1] + sm[2] + sm[3];
}

__global__ void ln_kernel(const float* __restrict__ agg, const float* __restrict__ bias,
                          const float* __restrict__ g, const float* __restrict__ beta,
                          const float* __restrict__ resid, float* __restrict__ outp,
                          int do_relu) {
    __shared__ float sm[4];
    const int n = blockIdx.x;
    const int t = threadIdx.x;  // 256 threads, 3 elems each
    float v[3];
    float s = 0.f;
#pragma unroll
    for (int i = 0; i < 3; ++i) {
        const int d = t + i * 256;
        v[i] = agg[(size_t)n * DIM + d] + bias[d];
        s += v[i];
    }
    const float mu = block_reduce_sum(s, sm) * (1.0f / DIM);
    float s2 = 0.f;
#pragma unroll
    for (int i = 0; i < 3; ++i) {
        const float c = v[i] - mu;
        s2 += c * c;
    }
    const float var = block_reduce_sum(s2, sm) * (1.0f / DIM);
    const float inv = rsqrtf(var + LN_EPS);
#pragma unroll
    for (int i = 0; i < 3; ++i) {
        const int d = t + i * 256;
        float o = (v[i] - mu) * inv * g[d] + beta[d];
        if (resid != nullptr) o += resid[(size_t)n * DIM + d];
        if (do_relu) o = fmaxf(o, 0.f);
        outp[(size_t)n * DIM + d] = o;
    }
}

extern "C" void kernel_launch(void* const* d_in, const int* in_sizes, int n_in,
                              void* d_out, int out_size, void* d_ws, size_t ws_size,
                              hipStream_t stream) {
    const float* x      = (const float*)d_in[0];
    const int*   ei     = (const int*)d_in[1];   // [2, E]
    const int*   et     = (const int*)d_in[2];   // [E]
    const float* W_rel  = (const float*)d_in[3]; // [L, R, D, D]
    const float* W_root = (const float*)d_in[4]; // [L, D, D]
    const float* bias   = (const float*)d_in[5]; // [L, D]
    const float* ln_g   = (const float*)d_in[6]; // [L, D]
    const float* ln_b   = (const float*)d_in[7]; // [L, D]
    float* out = (float*)d_out;

    // workspace: h1 [N,D] | sums [N,D] | cnt [N,R]
    float* h1   = (float*)d_ws;
    float* sums = h1 + (size_t)N_NODES * DIM;
    int*   cnt  = (int*)(sums + (size_t)N_NODES * DIM);

    // agg lives in d_out (memset at each layer start; final LN writes in place)
    float* agg = out;

    hipMemsetAsync(cnt, 0, (size_t)N_NODES * N_REL * sizeof(int), stream);
    count_kernel<<<(N_EDGES + 255) / 256, 256, 0, stream>>>(ei, et, cnt);

    const int scatter_grid = (N_EDGES * (DIM / 4) + 255) / 256;
    const dim3 gemm_grid((N_NODES + BM - 1) / BM, DIM / BN);

    for (int l = 0; l < N_LAYERS; ++l) {
        const float* hin = (l == 0) ? x : h1;
        float* hout = (l == 0) ? h1 : out;

        hipMemsetAsync(agg, 0, (size_t)N_NODES * DIM * sizeof(float), stream);

        for (int r = 0; r < N_REL; ++r) {
            hipMemsetAsync(sums, 0, (size_t)N_NODES * DIM * sizeof(float), stream);
            scatter_kernel<<<scatter_grid, 256, 0, stream>>>(hin, ei, et, sums, r);
            gemm_acc<<<gemm_grid, 256, 0, stream>>>(
                sums, W_rel + (((size_t)l * N_REL + r) * DIM * DIM), agg, cnt, r);
        }
        // root transform: agg += hin @ W_root[l]
        gemm_acc<<<gemm_grid, 256, 0, stream>>>(
            hin, W_root + (size_t)l * DIM * DIM, agg, nullptr, 0);

        // bias + LN (+residual for l>0) (+relu for l<L-1); in-place over agg
        ln_kernel<<<N_NODES, 256, 0, stream>>>(
            agg, bias + l * DIM, ln_g + l * DIM, ln_b + l * DIM,
            (l > 0) ? hin : nullptr, hout, (l < N_LAYERS - 1) ? 1 : 0);
    }
}

// Round 3
// 6847.444 us; speedup vs baseline: 2.0297x; 2.0297x over previous
//
#include <hip/hip_runtime.h>

#define N_NODES 30000
#define N_EDGES 200000
#define DIM 768
#define N_REL 10
#define N_LAYERS 2
#define LN_EPS 1e-5f
#define W_ELEMS (DIM * DIM)

typedef _Float16 f16;
typedef _Float16 f16x4 __attribute__((ext_vector_type(4)));
typedef _Float16 f16x8 __attribute__((ext_vector_type(8)));
typedef float f32x4 __attribute__((ext_vector_type(4)));

#define GLD(gaddr, laddr)                                                              \
    __builtin_amdgcn_global_load_lds((const __attribute__((address_space(1))) void*)(gaddr), \
                                     (__attribute__((address_space(3))) void*)(laddr), 16, 0, 0)

// ---- count edges per (dst,rel) + per-rel histogram (layer-invariant) ----
__global__ void count_kernel(const int* __restrict__ ei, const int* __restrict__ et,
                             int* __restrict__ cnt, int* __restrict__ hist) {
    int e = blockIdx.x * blockDim.x + threadIdx.x;
    if (e >= N_EDGES) return;
    int dst = ei[N_EDGES + e];
    int r = et[e];
    atomicAdd(&cnt[dst * N_REL + r], 1);
    atomicAdd(&hist[r], 1);
}

__global__ void prefix_kernel(const int* __restrict__ hist, int* __restrict__ rstart,
                              int* __restrict__ cursor) {
    if (blockIdx.x == 0 && threadIdx.x == 0) {
        int a = 0;
        for (int r = 0; r < N_REL; ++r) { rstart[r] = a; cursor[r] = a; a += hist[r]; }
        rstart[N_REL] = a;
    }
}

__global__ void bucket_kernel(const int* __restrict__ et, int* __restrict__ cursor,
                              int* __restrict__ ebuck) {
    int e = blockIdx.x * blockDim.x + threadIdx.x;
    if (e >= N_EDGES) return;
    int r = et[e];
    int pos = atomicAdd(&cursor[r], 1);
    ebuck[pos] = e;
}

// ---- f32 -> f16 elementwise (x into hf16) ----
__global__ void convx_kernel(const float* __restrict__ in, f16* __restrict__ out) {
    int idx = blockIdx.x * blockDim.x + threadIdx.x;
    if (idx >= N_NODES * DIM / 4) return;
    const float4 v = *reinterpret_cast<const float4*>(in + (size_t)idx * 4);
    f16x4 o = {(f16)v.x, (f16)v.y, (f16)v.z, (f16)v.w};
    *reinterpret_cast<f16x4*>(out + (size_t)idx * 4) = o;
}

// ---- W convert + transpose: WT[s][j][k] = Wsrc[s][k][j] as f16 ----
__global__ void convw_kernel(const float* __restrict__ Wrel, const float* __restrict__ Wroot,
                             f16* __restrict__ WT, int layer) {
    __shared__ float tile[32][33];
    const int s = blockIdx.z;
    const float* src = (s < N_REL) ? (Wrel + ((size_t)layer * N_REL + s) * W_ELEMS)
                                   : (Wroot + (size_t)layer * W_ELEMS);
    const int k0 = blockIdx.x * 32;
    const int j0 = blockIdx.y * 32;
    const int tx = threadIdx.x;  // 0..31
    const int ty = threadIdx.y;  // 0..7
#pragma unroll
    for (int i = 0; i < 4; ++i)
        tile[ty + i * 8][tx] = src[(size_t)(k0 + ty + i * 8) * DIM + j0 + tx];
    __syncthreads();
    f16* dst = WT + (size_t)s * W_ELEMS;
#pragma unroll
    for (int i = 0; i < 4; ++i)
        dst[(size_t)(j0 + ty + i * 8) * DIM + k0 + tx] = (f16)tile[tx][ty + i * 8];
}

// ---- f16 MFMA GEMM: Z[:, slab-cols] = A @ WT[slab]^T (WT stored [j][k]) ----
// grid.x = M tiles (128 rows), grid.y = (slabs_in_launch * 6) N tiles (128 cols)
// Zout != null: store f16 into Zg [N, zld];  else store f32 into aggout [N, DIM]
__global__ void __launch_bounds__(256)
gemm_kernel(const f16* __restrict__ A, const f16* __restrict__ WT, int slab0,
            f16* __restrict__ Zout, int zld, float* __restrict__ aggout) {
    __shared__ alignas(128) f16 As[128 * 32];
    __shared__ alignas(128) f16 Bs[128 * 32];

    const int t = threadIdx.x;
    const int wv = t >> 6, lane = t & 63;
    const int wr = wv >> 1, wc = wv & 1;
    const int m0 = blockIdx.x * 128;
    const int sl = blockIdx.y / 6;
    const int jt = blockIdx.y % 6;
    const int slab = slab0 + sl;
    const f16* B = WT + (size_t)slab * W_ELEMS + (size_t)(jt * 128) * DIM;

    // staging addresses: issue q covers rows 64q..64q+63; thread t -> row t/4, k-chunk (t&3)*8
    const int lr = t >> 2;
    const int kc = (t & 3) * 8;
    int ar0 = m0 + lr;      if (ar0 > N_NODES - 1) ar0 = N_NODES - 1;
    int ar1 = m0 + 64 + lr; if (ar1 > N_NODES - 1) ar1 = N_NODES - 1;
    const f16* ga0 = A + (size_t)ar0 * DIM + kc;
    const f16* ga1 = A + (size_t)ar1 * DIM + kc;
    const f16* gb0 = B + (size_t)lr * DIM + kc;
    const f16* gb1 = B + (size_t)(64 + lr) * DIM + kc;
    char* lA0 = (char*)As + wv * 1024;
    char* lA1 = (char*)As + 4096 + wv * 1024;
    char* lB0 = (char*)Bs + wv * 1024;
    char* lB1 = (char*)Bs + 4096 + wv * 1024;

    f32x4 acc[4][4];
#pragma unroll
    for (int i = 0; i < 4; ++i)
#pragma unroll
        for (int j = 0; j < 4; ++j) acc[i][j] = (f32x4){0.f, 0.f, 0.f, 0.f};

    for (int k0 = 0; k0 < DIM; k0 += 32) {
        GLD(ga0 + k0, lA0);
        GLD(ga1 + k0, lA1);
        GLD(gb0 + k0, lB0);
        GLD(gb1 + k0, lB1);
        __syncthreads();  // compiler emits vmcnt(0) drain before barrier

        f16x8 a[4], b[4];
#pragma unroll
        for (int i = 0; i < 4; ++i) {
            a[i] = *(const f16x8*)&As[(wr * 64 + i * 16 + (lane & 15)) * 32 + (lane >> 4) * 8];
            b[i] = *(const f16x8*)&Bs[(wc * 64 + i * 16 + (lane & 15)) * 32 + (lane >> 4) * 8];
        }
#pragma unroll
        for (int mi = 0; mi < 4; ++mi)
#pragma unroll
            for (int ni = 0; ni < 4; ++ni)
                acc[mi][ni] = __builtin_amdgcn_mfma_f32_16x16x32_f16(a[mi], b[ni], acc[mi][ni], 0, 0, 0);
        __syncthreads();
    }

    const int lrow = (lane >> 4) * 4, lcol = lane & 15;
    if (Zout != nullptr) {
        const int c0 = sl * DIM + jt * 128 + wc * 64;
#pragma unroll
        for (int mi = 0; mi < 4; ++mi)
#pragma unroll
            for (int q = 0; q < 4; ++q) {
                const int row = m0 + wr * 64 + mi * 16 + lrow + q;
                if (row >= N_NODES) continue;
                f16* zp = Zout + (size_t)row * zld + c0 + lcol;
#pragma unroll
                for (int ni = 0; ni < 4; ++ni) zp[ni * 16] = (f16)acc[mi][ni][q];
            }
    } else {
        const int c0 = jt * 128 + wc * 64;
#pragma unroll
        for (int mi = 0; mi < 4; ++mi)
#pragma unroll
            for (int q = 0; q < 4; ++q) {
                const int row = m0 + wr * 64 + mi * 16 + lrow + q;
                if (row >= N_NODES) continue;
                float* op = aggout + (size_t)row * DIM + c0 + lcol;
#pragma unroll
                for (int ni = 0; ni < 4; ++ni) op[ni * 16] = acc[mi][ni][q];
            }
    }
}

// ---- persistent scatter: agg[dst] += Z[src, rel-slice] / cnt[dst,rel] ----
__global__ void __launch_bounds__(192)
scatter_kernel(const f16* __restrict__ Z, int zld, const int* __restrict__ ebuck,
               const int* __restrict__ rstart, const int* __restrict__ ei,
               const int* __restrict__ et, const int* __restrict__ cnt,
               float* __restrict__ agg, int r0, int nrel) {
    const int lo = rstart[r0];
    const int hi = rstart[r0 + nrel];
    const int t = threadIdx.x;  // 192 threads, 4 f16 each
    for (int i = lo + blockIdx.x; i < hi; i += gridDim.x) {
        const int e = ebuck[i];
        const int r = et[e];
        const int src = ei[e];
        const int dst = ei[N_EDGES + e];
        const float inv = 1.0f / (float)cnt[dst * N_REL + r];
        const f16* zr = Z + (size_t)src * zld + (size_t)(r - r0) * DIM;
        const f16x4 v = *reinterpret_cast<const f16x4*>(zr + t * 4);
        float* ap = agg + (size_t)dst * DIM + t * 4;
        atomicAdd(ap + 0, (float)v[0] * inv);
        atomicAdd(ap + 1, (float)v[1] * inv);
        atomicAdd(ap + 2, (float)v[2] * inv);
        atomicAdd(ap + 3, (float)v[3] * inv);
    }
}

// ---- bias + LN + optional residual(f16) + optional relu; f32 and/or f16 out ----
__device__ __forceinline__ float block_reduce_sum(float v, float* sm) {
#pragma unroll
    for (int o = 32; o > 0; o >>= 1) v += __shfl_down(v, o, 64);
    const int wid = threadIdx.x >> 6;
    const int lane = threadIdx.x & 63;
    __syncthreads();
    if (lane == 0) sm[wid] = v;
    __syncthreads();
    return sm[0] + sm[1] + sm[2] + sm[3];
}

__global__ void __launch_bounds__(256)
ln_kernel(const float* __restrict__ agg, const float* __restrict__ bias,
          const float* __restrict__ g, const float* __restrict__ beta,
          const f16* __restrict__ resid16, float* __restrict__ outf32,
          f16* __restrict__ outf16, int do_relu) {
    __shared__ float sm[4];
    const int n = blockIdx.x;
    const int t = threadIdx.x;
    float v[3];
    float s = 0.f;
#pragma unroll
    for (int i = 0; i < 3; ++i) {
        const int d = t + i * 256;
        v[i] = agg[(size_t)n * DIM + d] + bias[d];
        s += v[i];
    }
    const float mu = block_reduce_sum(s, sm) * (1.0f / DIM);
    float s2 = 0.f;
#pragma unroll
    for (int i = 0; i < 3; ++i) {
        const float c = v[i] - mu;
        s2 += c * c;
    }
    const float var = block_reduce_sum(s2, sm) * (1.0f / DIM);
    const float inv = rsqrtf(var + LN_EPS);
#pragma unroll
    for (int i = 0; i < 3; ++i) {
        const int d = t + i * 256;
        float o = (v[i] - mu) * inv * g[d] + beta[d];
        if (resid16 != nullptr) o += (float)resid16[(size_t)n * DIM + d];
        if (do_relu) o = fmaxf(o, 0.f);
        if (outf32 != nullptr) outf32[(size_t)n * DIM + d] = o;
        if (outf16 != nullptr) outf16[(size_t)n * DIM + d] = (f16)o;
    }
}

extern "C" void kernel_launch(void* const* d_in, const int* in_sizes, int n_in,
                              void* d_out, int out_size, void* d_ws, size_t ws_size,
                              hipStream_t stream) {
    const float* x      = (const float*)d_in[0];
    const int*   ei     = (const int*)d_in[1];
    const int*   et     = (const int*)d_in[2];
    const float* W_rel  = (const float*)d_in[3];
    const float* W_root = (const float*)d_in[4];
    const float* bias   = (const float*)d_in[5];
    const float* ln_g   = (const float*)d_in[6];
    const float* ln_b   = (const float*)d_in[7];
    float* out = (float*)d_out;

    // workspace carve-out
    char* w = (char*)d_ws;
    auto alloc = [&](size_t bytes) -> char* {
        char* p = w;
        w += (bytes + 255) & ~(size_t)255;
        return p;
    };
    f16* hf16   = (f16*)alloc((size_t)N_NODES * DIM * 2);
    f16* WT     = (f16*)alloc((size_t)(N_REL + 1) * W_ELEMS * 2);
    int* cnt    = (int*)alloc((size_t)N_NODES * N_REL * 4);
    int* hist   = (int*)alloc(64);
    int* rstart = (int*)alloc(64);
    int* cursor = (int*)alloc(64);
    int* ebuck  = (int*)alloc((size_t)N_EDGES * 4);
    const size_t used = (size_t)(w - (char*)d_ws);
    const size_t zrel_bytes = (size_t)N_NODES * DIM * 2;  // one relation slab of Z
    int rpg = (ws_size > used) ? (int)((ws_size - used) / zrel_bytes) : 1;
    if (rpg < 1) rpg = 1;
    if (rpg > N_REL) rpg = N_REL;
    f16* Zg = (f16*)w;

    hipMemsetAsync(cnt, 0, (size_t)N_NODES * N_REL * 4, stream);
    hipMemsetAsync(hist, 0, 64, stream);
    count_kernel<<<(N_EDGES + 255) / 256, 256, 0, stream>>>(ei, et, cnt, hist);
    prefix_kernel<<<1, 64, 0, stream>>>(hist, rstart, cursor);
    bucket_kernel<<<(N_EDGES + 255) / 256, 256, 0, stream>>>(et, cursor, ebuck);
    convx_kernel<<<(N_NODES * DIM / 4 + 255) / 256, 256, 0, stream>>>(x, hf16);

    const int mt = (N_NODES + 127) / 128;  // 235
    for (int l = 0; l < N_LAYERS; ++l) {
        convw_kernel<<<dim3(24, 24, N_REL + 1), dim3(32, 8), 0, stream>>>(W_rel, W_root, WT, l);

        // root transform writes agg (= d_out) densely first
        gemm_kernel<<<dim3(mt, 6), 256, 0, stream>>>(hf16, WT, N_REL, (f16*)nullptr, 0, out);

        for (int g0 = 0; g0 < N_REL; g0 += rpg) {
            const int nr = (g0 + rpg <= N_REL) ? rpg : (N_REL - g0);
            gemm_kernel<<<dim3(mt, nr * 6), 256, 0, stream>>>(hf16, WT, g0, Zg, nr * DIM, nullptr);
            scatter_kernel<<<4096, 192, 0, stream>>>(Zg, nr * DIM, ebuck, rstart, ei, et, cnt,
                                                     out, g0, nr);
        }

        ln_kernel<<<N_NODES, 256, 0, stream>>>(
            out, bias + (size_t)l * DIM, ln_g + (size_t)l * DIM, ln_b + (size_t)l * DIM,
            (l > 0) ? hf16 : nullptr,                  // residual (h_prev as f16)
            (l == N_LAYERS - 1) ? out : nullptr,       // final f32 output
            (l < N_LAYERS - 1) ? hf16 : nullptr,       // next layer's f16 input
            (l < N_LAYERS - 1) ? 1 : 0);
    }
}

// Round 4
// 1861.229 us; speedup vs baseline: 7.4673x; 3.6790x over previous
//
#include <hip/hip_runtime.h>

#define N_NODES 30000
#define N_EDGES 200000
#define DIM 768
#define N_REL 10
#define N_LAYERS 2
#define LN_EPS 1e-5f
#define W_ELEMS (DIM * DIM)

typedef _Float16 f16;
typedef _Float16 f16x4 __attribute__((ext_vector_type(4)));
typedef _Float16 f16x8 __attribute__((ext_vector_type(8)));
typedef float f32x4 __attribute__((ext_vector_type(4)));

#define GLD(gaddr, laddr)                                                              \
    __builtin_amdgcn_global_load_lds((const __attribute__((address_space(1))) void*)(gaddr), \
                                     (__attribute__((address_space(3))) void*)(laddr), 16, 0, 0)

// ---- count edges per (dst,rel) + degree per dst (layer-invariant) ----
__global__ void count_kernel(const int* __restrict__ ei, const int* __restrict__ et,
                             int* __restrict__ cnt, int* __restrict__ deg) {
    int e = blockIdx.x * blockDim.x + threadIdx.x;
    if (e >= N_EDGES) return;
    int dst = ei[N_EDGES + e];
    int r = et[e];
    atomicAdd(&cnt[dst * N_REL + r], 1);
    atomicAdd(&deg[dst], 1);
}

// ---- single-block scan: row_start = exclusive prefix of deg; cursor = copy ----
#define SCAN_CHUNK 118  // 256*118 = 30208 >= N_NODES
__global__ void scan_kernel(const int* __restrict__ deg, int* __restrict__ row_start,
                            int* __restrict__ cursor) {
    __shared__ int part[256];
    __shared__ int off[257];
    const int t = threadIdx.x;
    const int c0 = t * SCAN_CHUNK;
    int s = 0;
    for (int i = 0; i < SCAN_CHUNK; ++i) {
        const int idx = c0 + i;
        if (idx < N_NODES) s += deg[idx];
    }
    part[t] = s;
    __syncthreads();
    if (t == 0) {
        int a = 0;
        for (int i = 0; i < 256; ++i) { off[i] = a; a += part[i]; }
        off[256] = a;
        row_start[N_NODES] = a;
    }
    __syncthreads();
    int a = off[t];
    for (int i = 0; i < SCAN_CHUNK; ++i) {
        const int idx = c0 + i;
        if (idx < N_NODES) {
            row_start[idx] = a;
            cursor[idx] = a;
            a += deg[idx];
        }
    }
}

// ---- fill CSR: pack = (rel<<16) | src, grouped by dst ----
__global__ void fill_kernel(const int* __restrict__ ei, const int* __restrict__ et,
                            int* __restrict__ cursor, int* __restrict__ pack) {
    int e = blockIdx.x * blockDim.x + threadIdx.x;
    if (e >= N_EDGES) return;
    int dst = ei[N_EDGES + e];
    int pos = atomicAdd(&cursor[dst], 1);
    pack[pos] = (et[e] << 16) | ei[e];
}

// ---- f32 -> f16 elementwise (x into hf16) ----
__global__ void convx_kernel(const float* __restrict__ in, f16* __restrict__ out) {
    int idx = blockIdx.x * blockDim.x + threadIdx.x;
    if (idx >= N_NODES * DIM / 4) return;
    const float4 v = *reinterpret_cast<const float4*>(in + (size_t)idx * 4);
    f16x4 o = {(f16)v.x, (f16)v.y, (f16)v.z, (f16)v.w};
    *reinterpret_cast<f16x4*>(out + (size_t)idx * 4) = o;
}

// ---- W convert + transpose: WT[s][j][k] = Wsrc[s][k][j] as f16 ----
__global__ void convw_kernel(const float* __restrict__ Wrel, const float* __restrict__ Wroot,
                             f16* __restrict__ WT, int layer) {
    __shared__ float tile[32][33];
    const int s = blockIdx.z;
    const float* src = (s < N_REL) ? (Wrel + ((size_t)layer * N_REL + s) * W_ELEMS)
                                   : (Wroot + (size_t)layer * W_ELEMS);
    const int k0 = blockIdx.x * 32;
    const int j0 = blockIdx.y * 32;
    const int tx = threadIdx.x;  // 0..31
    const int ty = threadIdx.y;  // 0..7
#pragma unroll
    for (int i = 0; i < 4; ++i)
        tile[ty + i * 8][tx] = src[(size_t)(k0 + ty + i * 8) * DIM + j0 + tx];
    __syncthreads();
    f16* dst = WT + (size_t)s * W_ELEMS;
#pragma unroll
    for (int i = 0; i < 4; ++i)
        dst[(size_t)(j0 + ty + i * 8) * DIM + k0 + tx] = (f16)tile[tx][ty + i * 8];
}

// ---- f16 MFMA GEMM: Z[:, slab-cols] = A @ WT[slab]^T (WT stored [j][k]) ----
__global__ void __launch_bounds__(256)
gemm_kernel(const f16* __restrict__ A, const f16* __restrict__ WT, int slab0,
            f16* __restrict__ Zout, int zld, float* __restrict__ aggout) {
    __shared__ alignas(128) f16 As[128 * 32];
    __shared__ alignas(128) f16 Bs[128 * 32];

    const int t = threadIdx.x;
    const int wv = t >> 6, lane = t & 63;
    const int wr = wv >> 1, wc = wv & 1;
    const int m0 = blockIdx.x * 128;
    const int sl = blockIdx.y / 6;
    const int jt = blockIdx.y % 6;
    const int slab = slab0 + sl;
    const f16* B = WT + (size_t)slab * W_ELEMS + (size_t)(jt * 128) * DIM;

    const int lr = t >> 2;
    const int kc = (t & 3) * 8;
    int ar0 = m0 + lr;      if (ar0 > N_NODES - 1) ar0 = N_NODES - 1;
    int ar1 = m0 + 64 + lr; if (ar1 > N_NODES - 1) ar1 = N_NODES - 1;
    const f16* ga0 = A + (size_t)ar0 * DIM + kc;
    const f16* ga1 = A + (size_t)ar1 * DIM + kc;
    const f16* gb0 = B + (size_t)lr * DIM + kc;
    const f16* gb1 = B + (size_t)(64 + lr) * DIM + kc;
    char* lA0 = (char*)As + wv * 1024;
    char* lA1 = (char*)As + 4096 + wv * 1024;
    char* lB0 = (char*)Bs + wv * 1024;
    char* lB1 = (char*)Bs + 4096 + wv * 1024;

    f32x4 acc[4][4];
#pragma unroll
    for (int i = 0; i < 4; ++i)
#pragma unroll
        for (int j = 0; j < 4; ++j) acc[i][j] = (f32x4){0.f, 0.f, 0.f, 0.f};

    for (int k0 = 0; k0 < DIM; k0 += 32) {
        GLD(ga0 + k0, lA0);
        GLD(ga1 + k0, lA1);
        GLD(gb0 + k0, lB0);
        GLD(gb1 + k0, lB1);
        __syncthreads();

        f16x8 a[4], b[4];
#pragma unroll
        for (int i = 0; i < 4; ++i) {
            a[i] = *(const f16x8*)&As[(wr * 64 + i * 16 + (lane & 15)) * 32 + (lane >> 4) * 8];
            b[i] = *(const f16x8*)&Bs[(wc * 64 + i * 16 + (lane & 15)) * 32 + (lane >> 4) * 8];
        }
#pragma unroll
        for (int mi = 0; mi < 4; ++mi)
#pragma unroll
            for (int ni = 0; ni < 4; ++ni)
                acc[mi][ni] = __builtin_amdgcn_mfma_f32_16x16x32_f16(a[mi], b[ni], acc[mi][ni], 0, 0, 0);
        __syncthreads();
    }

    const int lrow = (lane >> 4) * 4, lcol = lane & 15;
    if (Zout != nullptr) {
        const int c0 = sl * DIM + jt * 128 + wc * 64;
#pragma unroll
        for (int mi = 0; mi < 4; ++mi)
#pragma unroll
            for (int q = 0; q < 4; ++q) {
                const int row = m0 + wr * 64 + mi * 16 + lrow + q;
                if (row >= N_NODES) continue;
                f16* zp = Zout + (size_t)row * zld + c0 + lcol;
#pragma unroll
                for (int ni = 0; ni < 4; ++ni) zp[ni * 16] = (f16)acc[mi][ni][q];
            }
    } else {
        const int c0 = jt * 128 + wc * 64;
#pragma unroll
        for (int mi = 0; mi < 4; ++mi)
#pragma unroll
            for (int q = 0; q < 4; ++q) {
                const int row = m0 + wr * 64 + mi * 16 + lrow + q;
                if (row >= N_NODES) continue;
                float* op = aggout + (size_t)row * DIM + c0 + lcol;
#pragma unroll
                for (int ni = 0; ni < 4; ++ni) op[ni * 16] = acc[mi][ni][q];
            }
    }
}

// ---- gather: agg[dst] += sum_e Z[src_e, rel-slice] / cnt[dst,rel_e]; no atomics ----
__global__ void __launch_bounds__(192)
gather_kernel(const f16* __restrict__ Z, int zld, const int* __restrict__ row_start,
              const int* __restrict__ pack, const int* __restrict__ cnt,
              float* __restrict__ agg, int g0, int nr) {
    const int dst = blockIdx.x;
    const int lo = row_start[dst];
    const int hi = row_start[dst + 1];
    const int t = threadIdx.x;  // 192 threads x 4 f16
    float a0 = 0.f, a1 = 0.f, a2 = 0.f, a3 = 0.f;
    bool hit = false;
    for (int i = lo; i < hi; ++i) {
        const int p = pack[i];
        const int r = p >> 16;
        if (r < g0 || r >= g0 + nr) continue;
        const int src = p & 0xffff;
        const float inv = 1.0f / (float)cnt[dst * N_REL + r];
        const f16x4 v = *reinterpret_cast<const f16x4*>(
            Z + (size_t)src * zld + (size_t)(r - g0) * DIM + t * 4);
        a0 += (float)v[0] * inv;
        a1 += (float)v[1] * inv;
        a2 += (float)v[2] * inv;
        a3 += (float)v[3] * inv;
        hit = true;
    }
    if (hit) {  // uniform across block
        float* ap = agg + (size_t)dst * DIM + t * 4;
        float4 c = *reinterpret_cast<float4*>(ap);
        c.x += a0; c.y += a1; c.z += a2; c.w += a3;
        *reinterpret_cast<float4*>(ap) = c;
    }
}

// ---- bias + LN + optional residual(f16) + optional relu; f32 and/or f16 out ----
__device__ __forceinline__ float block_reduce_sum(float v, float* sm) {
#pragma unroll
    for (int o = 32; o > 0; o >>= 1) v += __shfl_down(v, o, 64);
    const int wid = threadIdx.x >> 6;
    const int lane = threadIdx.x & 63;
    __syncthreads();
    if (lane == 0) sm[wid] = v;
    __syncthreads();
    return sm[0] + sm[1] + sm[2] + sm[3];
}

__global__ void __launch_bounds__(256)
ln_kernel(const float* __restrict__ agg, const float* __restrict__ bias,
          const float* __restrict__ g, const float* __restrict__ beta,
          const f16* __restrict__ resid16, float* __restrict__ outf32,
          f16* __restrict__ outf16, int do_relu) {
    __shared__ float sm[4];
    const int n = blockIdx.x;
    const int t = threadIdx.x;
    float v[3];
    float s = 0.f;
#pragma unroll
    for (int i = 0; i < 3; ++i) {
        const int d = t + i * 256;
        v[i] = agg[(size_t)n * DIM + d] + bias[d];
        s += v[i];
    }
    const float mu = block_reduce_sum(s, sm) * (1.0f / DIM);
    float s2 = 0.f;
#pragma unroll
    for (int i = 0; i < 3; ++i) {
        const float c = v[i] - mu;
        s2 += c * c;
    }
    const float var = block_reduce_sum(s2, sm) * (1.0f / DIM);
    const float inv = rsqrtf(var + LN_EPS);
#pragma unroll
    for (int i = 0; i < 3; ++i) {
        const int d = t + i * 256;
        float o = (v[i] - mu) * inv * g[d] + beta[d];
        if (resid16 != nullptr) o += (float)resid16[(size_t)n * DIM + d];
        if (do_relu) o = fmaxf(o, 0.f);
        if (outf32 != nullptr) outf32[(size_t)n * DIM + d] = o;
        if (outf16 != nullptr) outf16[(size_t)n * DIM + d] = (f16)o;
    }
}

extern "C" void kernel_launch(void* const* d_in, const int* in_sizes, int n_in,
                              void* d_out, int out_size, void* d_ws, size_t ws_size,
                              hipStream_t stream) {
    const float* x      = (const float*)d_in[0];
    const int*   ei     = (const int*)d_in[1];
    const int*   et     = (const int*)d_in[2];
    const float* W_rel  = (const float*)d_in[3];
    const float* W_root = (const float*)d_in[4];
    const float* bias   = (const float*)d_in[5];
    const float* ln_g   = (const float*)d_in[6];
    const float* ln_b   = (const float*)d_in[7];
    float* out = (float*)d_out;

    // workspace carve-out
    char* w = (char*)d_ws;
    auto alloc = [&](size_t bytes) -> char* {
        char* p = w;
        w += (bytes + 255) & ~(size_t)255;
        return p;
    };
    f16* hf16      = (f16*)alloc((size_t)N_NODES * DIM * 2);
    f16* WT        = (f16*)alloc((size_t)(N_REL + 1) * W_ELEMS * 2);
    int* cnt       = (int*)alloc((size_t)N_NODES * N_REL * 4);
    int* deg       = (int*)alloc((size_t)N_NODES * 4);
    int* row_start = (int*)alloc((size_t)(N_NODES + 1) * 4);
    int* cursor    = (int*)alloc((size_t)N_NODES * 4);
    int* pack      = (int*)alloc((size_t)N_EDGES * 4);
    const size_t used = (size_t)(w - (char*)d_ws);
    const size_t zrel_bytes = (size_t)N_NODES * DIM * 2;  // one relation slab of Z
    int rpg = (ws_size > used) ? (int)((ws_size - used) / zrel_bytes) : 1;
    if (rpg < 1) rpg = 1;
    if (rpg > N_REL) rpg = N_REL;
    f16* Zg = (f16*)w;

    hipMemsetAsync(cnt, 0, (size_t)N_NODES * N_REL * 4, stream);
    hipMemsetAsync(deg, 0, (size_t)N_NODES * 4, stream);
    count_kernel<<<(N_EDGES + 255) / 256, 256, 0, stream>>>(ei, et, cnt, deg);
    scan_kernel<<<1, 256, 0, stream>>>(deg, row_start, cursor);
    fill_kernel<<<(N_EDGES + 255) / 256, 256, 0, stream>>>(ei, et, cursor, pack);
    convx_kernel<<<(N_NODES * DIM / 4 + 255) / 256, 256, 0, stream>>>(x, hf16);

    const int mt = (N_NODES + 127) / 128;  // 235
    for (int l = 0; l < N_LAYERS; ++l) {
        convw_kernel<<<dim3(24, 24, N_REL + 1), dim3(32, 8), 0, stream>>>(W_rel, W_root, WT, l);

        // root transform writes agg (= d_out) densely first
        gemm_kernel<<<dim3(mt, 6), 256, 0, stream>>>(hf16, WT, N_REL, (f16*)nullptr, 0, out);

        for (int g0 = 0; g0 < N_REL; g0 += rpg) {
            const int nr = (g0 + rpg <= N_REL) ? rpg : (N_REL - g0);
            gemm_kernel<<<dim3(mt, nr * 6), 256, 0, stream>>>(hf16, WT, g0, Zg, nr * DIM, nullptr);
            gather_kernel<<<N_NODES, 192, 0, stream>>>(Zg, nr * DIM, row_start, pack, cnt,
                                                       out, g0, nr);
        }

        ln_kernel<<<N_NODES, 256, 0, stream>>>(
            out, bias + (size_t)l * DIM, ln_g + (size_t)l * DIM, ln_b + (size_t)l * DIM,
            (l > 0) ? hf16 : nullptr,
            (l == N_LAYERS - 1) ? out : nullptr,
            (l < N_LAYERS - 1) ? hf16 : nullptr,
            (l < N_LAYERS - 1) ? 1 : 0);
    }
}

// Round 5
// 1744.162 us; speedup vs baseline: 7.9685x; 1.0671x over previous
//
#include <hip/hip_runtime.h>

#define N_NODES 30000
#define N_EDGES 200000
#define DIM 768
#define N_REL 10
#define N_LAYERS 2
#define LN_EPS 1e-5f
#define W_ELEMS (DIM * DIM)
#define BKS 64  // GEMM k-step

typedef _Float16 f16;
typedef _Float16 f16x4 __attribute__((ext_vector_type(4)));
typedef _Float16 f16x8 __attribute__((ext_vector_type(8)));
typedef float f32x4 __attribute__((ext_vector_type(4)));

#define GLD(gaddr, laddr)                                                              \
    __builtin_amdgcn_global_load_lds((const __attribute__((address_space(1))) void*)(gaddr), \
                                     (__attribute__((address_space(3))) void*)(laddr), 16, 0, 0)

// ---- count edges per (dst,rel) + degree per dst (layer-invariant) ----
__global__ void count_kernel(const int* __restrict__ ei, const int* __restrict__ et,
                             int* __restrict__ cnt, int* __restrict__ deg) {
    int e = blockIdx.x * blockDim.x + threadIdx.x;
    if (e >= N_EDGES) return;
    int dst = ei[N_EDGES + e];
    int r = et[e];
    atomicAdd(&cnt[dst * N_REL + r], 1);
    atomicAdd(&deg[dst], 1);
}

// ---- single-block scan: row_start = exclusive prefix of deg; cursor = copy ----
#define SCAN_CHUNK 118  // 256*118 = 30208 >= N_NODES
__global__ void scan_kernel(const int* __restrict__ deg, int* __restrict__ row_start,
                            int* __restrict__ cursor) {
    __shared__ int part[256];
    __shared__ int off[257];
    const int t = threadIdx.x;
    const int c0 = t * SCAN_CHUNK;
    int s = 0;
    for (int i = 0; i < SCAN_CHUNK; ++i) {
        const int idx = c0 + i;
        if (idx < N_NODES) s += deg[idx];
    }
    part[t] = s;
    __syncthreads();
    if (t == 0) {
        int a = 0;
        for (int i = 0; i < 256; ++i) { off[i] = a; a += part[i]; }
        off[256] = a;
        row_start[N_NODES] = a;
    }
    __syncthreads();
    int a = off[t];
    for (int i = 0; i < SCAN_CHUNK; ++i) {
        const int idx = c0 + i;
        if (idx < N_NODES) {
            row_start[idx] = a;
            cursor[idx] = a;
            a += deg[idx];
        }
    }
}

// ---- fill CSR: pack = (rel<<16) | src, grouped by dst ----
__global__ void fill_kernel(const int* __restrict__ ei, const int* __restrict__ et,
                            int* __restrict__ cursor, int* __restrict__ pack) {
    int e = blockIdx.x * blockDim.x + threadIdx.x;
    if (e >= N_EDGES) return;
    int dst = ei[N_EDGES + e];
    int pos = atomicAdd(&cursor[dst], 1);
    pack[pos] = (et[e] << 16) | ei[e];
}

// ---- f32 -> f16 elementwise (x into hf16) ----
__global__ void convx_kernel(const float* __restrict__ in, f16* __restrict__ out) {
    int idx = blockIdx.x * blockDim.x + threadIdx.x;
    if (idx >= N_NODES * DIM / 4) return;
    const float4 v = *reinterpret_cast<const float4*>(in + (size_t)idx * 4);
    f16x4 o = {(f16)v.x, (f16)v.y, (f16)v.z, (f16)v.w};
    *reinterpret_cast<f16x4*>(out + (size_t)idx * 4) = o;
}

// ---- W convert + transpose: WT[s][j][k] = Wsrc[s][k][j] as f16 ----
__global__ void convw_kernel(const float* __restrict__ Wrel, const float* __restrict__ Wroot,
                             f16* __restrict__ WT, int layer) {
    __shared__ float tile[32][33];
    const int s = blockIdx.z;
    const float* src = (s < N_REL) ? (Wrel + ((size_t)layer * N_REL + s) * W_ELEMS)
                                   : (Wroot + (size_t)layer * W_ELEMS);
    const int k0 = blockIdx.x * 32;
    const int j0 = blockIdx.y * 32;
    const int tx = threadIdx.x;  // 0..31
    const int ty = threadIdx.y;  // 0..7
#pragma unroll
    for (int i = 0; i < 4; ++i)
        tile[ty + i * 8][tx] = src[(size_t)(k0 + ty + i * 8) * DIM + j0 + tx];
    __syncthreads();
    f16* dst = WT + (size_t)s * W_ELEMS;
#pragma unroll
    for (int i = 0; i < 4; ++i)
        dst[(size_t)(j0 + ty + i * 8) * DIM + k0 + tx] = (f16)tile[tx][ty + i * 8];
}

// ---- f16 MFMA GEMM: Z[:, slab-cols] = A @ WT[slab]^T (WT stored [j][k]) ----
// LDS tile [128][BKS=64 f16]; k-chunks (16 B) XOR-swizzled: LDS chunk c holds
// global chunk c ^ (row&7). Row stride = 128 B = 32 banks -> bank set by chunk
// only -> 2-way (free). global_load_lds dest stays linear (rule #21).
__global__ void __launch_bounds__(256)
gemm_kernel(const f16* __restrict__ A, const f16* __restrict__ WT, int slab0,
            f16* __restrict__ Zout, int zld, float* __restrict__ aggout) {
    __shared__ alignas(128) f16 As[128 * BKS];  // 16 KB
    __shared__ alignas(128) f16 Bs[128 * BKS];  // 16 KB

    const int t = threadIdx.x;
    const int wv = t >> 6, lane = t & 63;
    const int wr = wv >> 1, wc = wv & 1;
    const int m0 = blockIdx.x * 128;
    const int sl = blockIdx.y / 6;
    const int jt = blockIdx.y % 6;
    const f16* B = WT + (size_t)(slab0 + sl) * W_ELEMS + (size_t)(jt * 128) * DIM;

    // staging: 1024 16-B chunks per operand; issue q stages chunk q*256+t
    const f16* gA[4];
    const f16* gB[4];
    char* lA[4];
    char* lB[4];
#pragma unroll
    for (int q = 0; q < 4; ++q) {
        const int chunk = q * 256 + t;
        const int row = chunk >> 3;           // 0..127
        const int gk = (chunk & 7) ^ (row & 7);  // swizzled source chunk
        int arow = m0 + row;
        if (arow > N_NODES - 1) arow = N_NODES - 1;
        gA[q] = A + (size_t)arow * DIM + gk * 8;
        gB[q] = B + (size_t)row * DIM + gk * 8;
        lA[q] = (char*)As + q * 4096 + wv * 1024;  // wave-uniform base; HW adds lane*16
        lB[q] = (char*)Bs + q * 4096 + wv * 1024;
    }

    f32x4 acc[4][4];
#pragma unroll
    for (int i = 0; i < 4; ++i)
#pragma unroll
        for (int j = 0; j < 4; ++j) acc[i][j] = (f32x4){0.f, 0.f, 0.f, 0.f};

    const int lr16 = lane & 15, lk = lane >> 4, l7 = lane & 7;

    for (int k0 = 0; k0 < DIM; k0 += BKS) {
#pragma unroll
        for (int q = 0; q < 4; ++q) {
            GLD(gA[q] + k0, lA[q]);
            GLD(gB[q] + k0, lB[q]);
        }
        __syncthreads();  // compiler emits vmcnt(0) drain before barrier

#pragma unroll
        for (int h = 0; h < 2; ++h) {
            f16x8 a[4], b[4];
            const int cp = (((h << 2) | lk) ^ l7) * 8;  // swizzled k-chunk, f16 units
#pragma unroll
            for (int i = 0; i < 4; ++i) {
                a[i] = *(const f16x8*)&As[(wr * 64 + i * 16 + lr16) * BKS + cp];
                b[i] = *(const f16x8*)&Bs[(wc * 64 + i * 16 + lr16) * BKS + cp];
            }
#pragma unroll
            for (int mi = 0; mi < 4; ++mi)
#pragma unroll
                for (int ni = 0; ni < 4; ++ni)
                    acc[mi][ni] =
                        __builtin_amdgcn_mfma_f32_16x16x32_f16(a[mi], b[ni], acc[mi][ni], 0, 0, 0);
        }
        __syncthreads();
    }

    const int lrow = (lane >> 4) * 4, lcol = lane & 15;
    if (Zout != nullptr) {
        const int c0 = sl * DIM + jt * 128 + wc * 64;
#pragma unroll
        for (int mi = 0; mi < 4; ++mi)
#pragma unroll
            for (int q = 0; q < 4; ++q) {
                const int row = m0 + wr * 64 + mi * 16 + lrow + q;
                if (row >= N_NODES) continue;
                f16* zp = Zout + (size_t)row * zld + c0 + lcol;
#pragma unroll
                for (int ni = 0; ni < 4; ++ni) zp[ni * 16] = (f16)acc[mi][ni][q];
            }
    } else {
        const int c0 = jt * 128 + wc * 64;
#pragma unroll
        for (int mi = 0; mi < 4; ++mi)
#pragma unroll
            for (int q = 0; q < 4; ++q) {
                const int row = m0 + wr * 64 + mi * 16 + lrow + q;
                if (row >= N_NODES) continue;
                float* op = aggout + (size_t)row * DIM + c0 + lcol;
#pragma unroll
                for (int ni = 0; ni < 4; ++ni) op[ni * 16] = acc[mi][ni][q];
            }
    }
}

// ---- gather: agg[dst] += sum_e Z[src_e, rel-slice] / cnt[dst,rel_e]; no atomics ----
__global__ void __launch_bounds__(192)
gather_kernel(const f16* __restrict__ Z, int zld, const int* __restrict__ row_start,
              const int* __restrict__ pack, const int* __restrict__ cnt,
              float* __restrict__ agg, int g0, int nr) {
    const int dst = blockIdx.x;
    const int lo = row_start[dst];
    const int hi = row_start[dst + 1];
    const int t = threadIdx.x;  // 192 threads x 4 f16
    float a0 = 0.f, a1 = 0.f, a2 = 0.f, a3 = 0.f;
    bool hit = false;
    for (int i = lo; i < hi; ++i) {
        const int p = pack[i];
        const int r = p >> 16;
        if (r < g0 || r >= g0 + nr) continue;
        const int src = p & 0xffff;
        const float inv = 1.0f / (float)cnt[dst * N_REL + r];
        const f16x4 v = *reinterpret_cast<const f16x4*>(
            Z + (size_t)src * zld + (size_t)(r - g0) * DIM + t * 4);
        a0 += (float)v[0] * inv;
        a1 += (float)v[1] * inv;
        a2 += (float)v[2] * inv;
        a3 += (float)v[3] * inv;
        hit = true;
    }
    if (hit) {  // uniform across block
        float* ap = agg + (size_t)dst * DIM + t * 4;
        float4 c = *reinterpret_cast<float4*>(ap);
        c.x += a0; c.y += a1; c.z += a2; c.w += a3;
        *reinterpret_cast<float4*>(ap) = c;
    }
}

// ---- bias + LN + optional residual(f16) + optional relu; f32 and/or f16 out ----
__device__ __forceinline__ float block_reduce_sum(float v, float* sm) {
#pragma unroll
    for (int o = 32; o > 0; o >>= 1) v += __shfl_down(v, o, 64);
    const int wid = threadIdx.x >> 6;
    const int lane = threadIdx.x & 63;
    __syncthreads();
    if (lane == 0) sm[wid] = v;
    __syncthreads();
    return sm[0] + sm[1] + sm[2] + sm[3];
}

__global__ void __launch_bounds__(256)
ln_kernel(const float* __restrict__ agg, const float* __restrict__ bias,
          const float* __restrict__ g, const float* __restrict__ beta,
          const f16* __restrict__ resid16, float* __restrict__ outf32,
          f16* __restrict__ outf16, int do_relu) {
    __shared__ float sm[4];
    const int n = blockIdx.x;
    const int t = threadIdx.x;
    float v[3];
    float s = 0.f;
#pragma unroll
    for (int i = 0; i < 3; ++i) {
        const int d = t + i * 256;
        v[i] = agg[(size_t)n * DIM + d] + bias[d];
        s += v[i];
    }
    const float mu = block_reduce_sum(s, sm) * (1.0f / DIM);
    float s2 = 0.f;
#pragma unroll
    for (int i = 0; i < 3; ++i) {
        const float c = v[i] - mu;
        s2 += c * c;
    }
    const float var = block_reduce_sum(s2, sm) * (1.0f / DIM);
    const float inv = rsqrtf(var + LN_EPS);
#pragma unroll
    for (int i = 0; i < 3; ++i) {
        const int d = t + i * 256;
        float o = (v[i] - mu) * inv * g[d] + beta[d];
        if (resid16 != nullptr) o += (float)resid16[(size_t)n * DIM + d];
        if (do_relu) o = fmaxf(o, 0.f);
        if (outf32 != nullptr) outf32[(size_t)n * DIM + d] = o;
        if (outf16 != nullptr) outf16[(size_t)n * DIM + d] = (f16)o;
    }
}

extern "C" void kernel_launch(void* const* d_in, const int* in_sizes, int n_in,
                              void* d_out, int out_size, void* d_ws, size_t ws_size,
                              hipStream_t stream) {
    const float* x      = (const float*)d_in[0];
    const int*   ei     = (const int*)d_in[1];
    const int*   et     = (const int*)d_in[2];
    const float* W_rel  = (const float*)d_in[3];
    const float* W_root = (const float*)d_in[4];
    const float* bias   = (const float*)d_in[5];
    const float* ln_g   = (const float*)d_in[6];
    const float* ln_b   = (const float*)d_in[7];
    float* out = (float*)d_out;

    // workspace carve-out
    char* w = (char*)d_ws;
    auto alloc = [&](size_t bytes) -> char* {
        char* p = w;
        w += (bytes + 255) & ~(size_t)255;
        return p;
    };
    f16* hf16      = (f16*)alloc((size_t)N_NODES * DIM * 2);
    f16* WT        = (f16*)alloc((size_t)(N_REL + 1) * W_ELEMS * 2);
    int* cnt       = (int*)alloc((size_t)N_NODES * N_REL * 4);
    int* deg       = (int*)alloc((size_t)N_NODES * 4);
    int* row_start = (int*)alloc((size_t)(N_NODES + 1) * 4);
    int* cursor    = (int*)alloc((size_t)N_NODES * 4);
    int* pack      = (int*)alloc((size_t)N_EDGES * 4);
    const size_t used = (size_t)(w - (char*)d_ws);
    const size_t zrel_bytes = (size_t)N_NODES * DIM * 2;  // one relation slab of Z
    int rpg = (ws_size > used) ? (int)((ws_size - used) / zrel_bytes) : 1;
    if (rpg < 1) rpg = 1;
    if (rpg > N_REL) rpg = N_REL;
    f16* Zg = (f16*)w;

    hipMemsetAsync(cnt, 0, (size_t)N_NODES * N_REL * 4, stream);
    hipMemsetAsync(deg, 0, (size_t)N_NODES * 4, stream);
    count_kernel<<<(N_EDGES + 255) / 256, 256, 0, stream>>>(ei, et, cnt, deg);
    scan_kernel<<<1, 256, 0, stream>>>(deg, row_start, cursor);
    fill_kernel<<<(N_EDGES + 255) / 256, 256, 0, stream>>>(ei, et, cursor, pack);
    convx_kernel<<<(N_NODES * DIM / 4 + 255) / 256, 256, 0, stream>>>(x, hf16);

    const int mt = (N_NODES + 127) / 128;  // 235
    for (int l = 0; l < N_LAYERS; ++l) {
        convw_kernel<<<dim3(24, 24, N_REL + 1), dim3(32, 8), 0, stream>>>(W_rel, W_root, WT, l);

        // root transform writes agg (= d_out) densely first
        gemm_kernel<<<dim3(mt, 6), 256, 0, stream>>>(hf16, WT, N_REL, (f16*)nullptr, 0, out);

        for (int g0 = 0; g0 < N_REL; g0 += rpg) {
            const int nr = (g0 + rpg <= N_REL) ? rpg : (N_REL - g0);
            gemm_kernel<<<dim3(mt, nr * 6), 256, 0, stream>>>(hf16, WT, g0, Zg, nr * DIM, nullptr);
            gather_kernel<<<N_NODES, 192, 0, stream>>>(Zg, nr * DIM, row_start, pack, cnt,
                                                       out, g0, nr);
        }

        ln_kernel<<<N_NODES, 256, 0, stream>>>(
            out, bias + (size_t)l * DIM, ln_g + (size_t)l * DIM, ln_b + (size_t)l * DIM,
            (l > 0) ? hf16 : nullptr,
            (l == N_LAYERS - 1) ? out : nullptr,
            (l < N_LAYERS - 1) ? hf16 : nullptr,
            (l < N_LAYERS - 1) ? 1 : 0);
    }
}

// Round 6
// 1611.398 us; speedup vs baseline: 8.6250x; 1.0824x over previous
//
#include <hip/hip_runtime.h>

#define N_NODES 30000
#define N_EDGES 200000
#define DIM 768
#define N_REL 10
#define N_LAYERS 2
#define LN_EPS 1e-5f
#define W_ELEMS (DIM * DIM)
#define BKS 64            // GEMM k-step
#define GT_MAX 1573       // upper bound on compact row-tiles: ceil(E/128)+10

typedef _Float16 f16;
typedef _Float16 f16x4 __attribute__((ext_vector_type(4)));
typedef _Float16 f16x8 __attribute__((ext_vector_type(8)));
typedef float f32x4 __attribute__((ext_vector_type(4)));

#define GLD(gaddr, laddr)                                                              \
    __builtin_amdgcn_global_load_lds((const __attribute__((address_space(1))) void*)(gaddr), \
                                     (__attribute__((address_space(3))) void*)(laddr), 16, 0, 0)

// ---- count: cnt[dst][r], deg[dst], per-rel distinct-src position map ----
__global__ void count_kernel(const int* __restrict__ ei, const int* __restrict__ et,
                             int* __restrict__ cnt, int* __restrict__ deg,
                             int* __restrict__ posmap, int* __restrict__ mr) {
    int e = blockIdx.x * blockDim.x + threadIdx.x;
    if (e >= N_EDGES) return;
    int src = ei[e];
    int dst = ei[N_EDGES + e];
    int r = et[e];
    atomicAdd(&cnt[dst * N_REL + r], 1);
    atomicAdd(&deg[dst], 1);
    const int idx = r * N_NODES + src;
    int old = atomicCAS(&posmap[idx], -1, -2);
    if (old == -1) {
        int p = atomicAdd(&mr[r], 1);
        posmap[idx] = p;  // visible to later kernels (kernel boundary)
    }
}

// ---- single-block scan: row_start = exclusive prefix of deg; cursor = copy ----
#define SCAN_CHUNK 118  // 256*118 = 30208 >= N_NODES
__global__ void scan_kernel(const int* __restrict__ deg, int* __restrict__ row_start,
                            int* __restrict__ cursor) {
    __shared__ int part[256];
    __shared__ int off[257];
    const int t = threadIdx.x;
    const int c0 = t * SCAN_CHUNK;
    int s = 0;
    for (int i = 0; i < SCAN_CHUNK; ++i) {
        const int idx = c0 + i;
        if (idx < N_NODES) s += deg[idx];
    }
    part[t] = s;
    __syncthreads();
    if (t == 0) {
        int a = 0;
        for (int i = 0; i < 256; ++i) { off[i] = a; a += part[i]; }
        off[256] = a;
        row_start[N_NODES] = a;
    }
    __syncthreads();
    int a = off[t];
    for (int i = 0; i < SCAN_CHUNK; ++i) {
        const int idx = c0 + i;
        if (idx < N_NODES) {
            row_start[idx] = a;
            cursor[idx] = a;
            a += deg[idx];
        }
    }
}

// ---- zbase (128-aligned prefix of mr) + tile->rel table ----
__global__ void zprep_kernel(const int* __restrict__ mr, int* __restrict__ zbase,
                             int* __restrict__ tile_rel) {
    if (blockIdx.x == 0 && threadIdx.x == 0) {
        int zc = 0, tc = 0;
        for (int r = 0; r < N_REL; ++r) {
            zbase[r] = zc;
            const int nt = (mr[r] + 127) >> 7;
            for (int i = 0; i < nt; ++i) tile_rel[tc + i] = r;
            tc += nt;
            zc += nt << 7;
        }
    }
}

// ---- fill CSR: pack = (rel<<24) | zrow; srclist[zrow] = src ----
__global__ void fill_kernel(const int* __restrict__ ei, const int* __restrict__ et,
                            const int* __restrict__ posmap, const int* __restrict__ zbase,
                            int* __restrict__ cursor, int* __restrict__ pack,
                            int* __restrict__ srclist) {
    int e = blockIdx.x * blockDim.x + threadIdx.x;
    if (e >= N_EDGES) return;
    int src = ei[e];
    int dst = ei[N_EDGES + e];
    int r = et[e];
    const int zrow = zbase[r] + posmap[r * N_NODES + src];
    int pos = atomicAdd(&cursor[dst], 1);
    pack[pos] = (r << 24) | zrow;
    srclist[zrow] = src;  // idempotent (same value from all writers)
}

// ---- f32 -> f16 elementwise (x into hf16) ----
__global__ void convx_kernel(const float* __restrict__ in, f16* __restrict__ out) {
    int idx = blockIdx.x * blockDim.x + threadIdx.x;
    if (idx >= N_NODES * DIM / 4) return;
    const float4 v = *reinterpret_cast<const float4*>(in + (size_t)idx * 4);
    f16x4 o = {(f16)v.x, (f16)v.y, (f16)v.z, (f16)v.w};
    *reinterpret_cast<f16x4*>(out + (size_t)idx * 4) = o;
}

// ---- W convert + transpose: WT[s][j][k] = Wsrc[s][k][j] as f16 ----
__global__ void convw_kernel(const float* __restrict__ Wrel, const float* __restrict__ Wroot,
                             f16* __restrict__ WT, int layer) {
    __shared__ float tile[32][33];
    const int s = blockIdx.z;
    const float* src = (s < N_REL) ? (Wrel + ((size_t)layer * N_REL + s) * W_ELEMS)
                                   : (Wroot + (size_t)layer * W_ELEMS);
    const int k0 = blockIdx.x * 32;
    const int j0 = blockIdx.y * 32;
    const int tx = threadIdx.x;  // 0..31
    const int ty = threadIdx.y;  // 0..7
#pragma unroll
    for (int i = 0; i < 4; ++i)
        tile[ty + i * 8][tx] = src[(size_t)(k0 + ty + i * 8) * DIM + j0 + tx];
    __syncthreads();
    f16* dst = WT + (size_t)s * W_ELEMS;
#pragma unroll
    for (int i = 0; i < 4; ++i)
        dst[(size_t)(j0 + ty + i * 8) * DIM + k0 + tx] = (f16)tile[tx][ty + i * 8];
}

// ---- f16 MFMA GEMM, 2-phase dbuf, XCD-chunk-swizzled 1-D grid ----
// compact mode (tile_rel != null): A rows gathered via srclist, Z f16 out
// root mode    (tile_rel == null): dense rows, slab N_REL, f32 agg out
// LDS [128][BKS=64]: 16B k-chunks XOR-swizzled (chunk c holds global chunk
// c^(row&7)); linear GLD dest + pre-swizzled global src + swizzled ds_read.
__global__ void __launch_bounds__(256)
gemm_kernel(const f16* __restrict__ A, const f16* __restrict__ WT,
            const int* __restrict__ srclist, const int* __restrict__ tile_rel,
            f16* __restrict__ Zout, float* __restrict__ aggout) {
    __shared__ alignas(128) f16 As[2][128 * BKS];  // 2 x 16 KB
    __shared__ alignas(128) f16 Bs[2][128 * BKS];  // 2 x 16 KB

    // bijective XCD chunk swizzle (m204): consecutive work ids -> same XCD
    const int nwg = gridDim.x;
    const int orig = blockIdx.x;
    const int qq = nwg >> 3, rr = nwg & 7, xc = orig & 7, oo = orig >> 3;
    const int wg = (xc < rr ? xc * (qq + 1) : rr * (qq + 1) + (xc - rr) * qq) + oo;
    const int gt = wg / 6, jt = wg % 6;  // jt fast: one A-tile's n-blocks share an XCD

    int rel;
    if (tile_rel != nullptr) {
        rel = tile_rel[gt];
        if (rel < 0) return;  // uniform early-exit (past end of real tiles)
    } else {
        rel = N_REL;
    }

    const int t = threadIdx.x;
    const int wv = t >> 6, lane = t & 63;
    const int wr = wv >> 1, wc = wv & 1;
    const f16* B = WT + (size_t)rel * W_ELEMS + (size_t)(jt * 128) * DIM;

    // staging sources: chunk = q*256+t -> row chunk>>3, swizzled k-chunk
    const f16* gA[4];
    const f16* gB[4];
#pragma unroll
    for (int q = 0; q < 4; ++q) {
        const int chunk = q * 256 + t;
        const int row = chunk >> 3;
        const int gk = (chunk & 7) ^ (row & 7);
        int arow;
        if (tile_rel != nullptr) {
            arow = srclist[gt * 128 + row];
        } else {
            arow = gt * 128 + row;
            if (arow > N_NODES - 1) arow = N_NODES - 1;
        }
        gA[q] = A + (size_t)arow * DIM + gk * 8;
        gB[q] = B + (size_t)row * DIM + gk * 8;
    }

    f32x4 acc[4][4];
#pragma unroll
    for (int i = 0; i < 4; ++i)
#pragma unroll
        for (int j = 0; j < 4; ++j) acc[i][j] = (f32x4){0.f, 0.f, 0.f, 0.f};

    const int lr16 = lane & 15, lk = lane >> 4, l7 = lane & 7;

    // prologue: stage K-step 0 into buf 0
#pragma unroll
    for (int q = 0; q < 4; ++q) {
        GLD(gA[q], (char*)As[0] + q * 4096 + wv * 1024);
        GLD(gB[q], (char*)Bs[0] + q * 4096 + wv * 1024);
    }
    __syncthreads();

    for (int ks = 0; ks < DIM / BKS; ++ks) {
        const int cur = ks & 1;
        if (ks < DIM / BKS - 1) {  // issue next tile's stage BEFORE compute
#pragma unroll
            for (int q = 0; q < 4; ++q) {
                GLD(gA[q] + (ks + 1) * BKS, (char*)As[cur ^ 1] + q * 4096 + wv * 1024);
                GLD(gB[q] + (ks + 1) * BKS, (char*)Bs[cur ^ 1] + q * 4096 + wv * 1024);
            }
        }
#pragma unroll
        for (int h = 0; h < 2; ++h) {
            f16x8 a[4], b[4];
            const int cp = (((h << 2) | lk) ^ l7) * 8;  // swizzled k-chunk (f16 units)
#pragma unroll
            for (int i = 0; i < 4; ++i) {
                a[i] = *(const f16x8*)&As[cur][(wr * 64 + i * 16 + lr16) * BKS + cp];
                b[i] = *(const f16x8*)&Bs[cur][(wc * 64 + i * 16 + lr16) * BKS + cp];
            }
#pragma unroll
            for (int mi = 0; mi < 4; ++mi)
#pragma unroll
                for (int ni = 0; ni < 4; ++ni)
                    acc[mi][ni] =
                        __builtin_amdgcn_mfma_f32_16x16x32_f16(a[mi], b[ni], acc[mi][ni], 0, 0, 0);
        }
        __syncthreads();  // single barrier/K-step: drains next-tile stage after compute
    }

    const int lrow = lk * 4, lcol = lr16;
    const int c0 = jt * 128 + wc * 64;
    if (tile_rel != nullptr) {
#pragma unroll
        for (int mi = 0; mi < 4; ++mi)
#pragma unroll
            for (int q = 0; q < 4; ++q) {
                const int z = gt * 128 + wr * 64 + mi * 16 + lrow + q;  // padding rows ok
                f16* zp = Zout + (size_t)z * DIM + c0 + lcol;
#pragma unroll
                for (int ni = 0; ni < 4; ++ni) zp[ni * 16] = (f16)acc[mi][ni][q];
            }
    } else {
#pragma unroll
        for (int mi = 0; mi < 4; ++mi)
#pragma unroll
            for (int q = 0; q < 4; ++q) {
                const int row = gt * 128 + wr * 64 + mi * 16 + lrow + q;
                if (row >= N_NODES) continue;
                float* op = aggout + (size_t)row * DIM + c0 + lcol;
#pragma unroll
                for (int ni = 0; ni < 4; ++ni) op[ni * 16] = acc[mi][ni][q];
            }
    }
}

// ---- gather: agg[dst] += sum_e Z[zrow_e] / cnt[dst,rel_e]; no atomics ----
__global__ void __launch_bounds__(192)
gather_kernel(const f16* __restrict__ Z, const int* __restrict__ row_start,
              const int* __restrict__ pack, const int* __restrict__ cnt,
              float* __restrict__ agg) {
    const int dst = blockIdx.x;
    const int lo = row_start[dst];
    const int hi = row_start[dst + 1];
    if (lo == hi) return;
    const int t = threadIdx.x;  // 192 threads x 4 f16
    float a0 = 0.f, a1 = 0.f, a2 = 0.f, a3 = 0.f;
    for (int i = lo; i < hi; ++i) {
        const int p = pack[i];
        const int r = p >> 24;
        const int zrow = p & 0xFFFFFF;
        const float inv = 1.0f / (float)cnt[dst * N_REL + r];
        const f16x4 v = *reinterpret_cast<const f16x4*>(Z + (size_t)zrow * DIM + t * 4);
        a0 += (float)v[0] * inv;
        a1 += (float)v[1] * inv;
        a2 += (float)v[2] * inv;
        a3 += (float)v[3] * inv;
    }
    float* ap = agg + (size_t)dst * DIM + t * 4;
    float4 c = *reinterpret_cast<float4*>(ap);
    c.x += a0; c.y += a1; c.z += a2; c.w += a3;
    *reinterpret_cast<float4*>(ap) = c;
}

// ---- bias + LN + optional residual(f16) + optional relu; f32 and/or f16 out ----
__device__ __forceinline__ float block_reduce_sum(float v, float* sm) {
#pragma unroll
    for (int o = 32; o > 0; o >>= 1) v += __shfl_down(v, o, 64);
    const int wid = threadIdx.x >> 6;
    const int lane = threadIdx.x & 63;
    __syncthreads();
    if (lane == 0) sm[wid] = v;
    __syncthreads();
    return sm[0] + sm[1] + sm[2] + sm[3];
}

__global__ void __launch_bounds__(256)
ln_kernel(const float* __restrict__ agg, const float* __restrict__ bias,
          const float* __restrict__ g, const float* __restrict__ beta,
          const f16* __restrict__ resid16, float* __restrict__ outf32,
          f16* __restrict__ outf16, int do_relu) {
    __shared__ float sm[4];
    const int n = blockIdx.x;
    const int t = threadIdx.x;
    float v[3];
    float s = 0.f;
#pragma unroll
    for (int i = 0; i < 3; ++i) {
        const int d = t + i * 256;
        v[i] = agg[(size_t)n * DIM + d] + bias[d];
        s += v[i];
    }
    const float mu = block_reduce_sum(s, sm) * (1.0f / DIM);
    float s2 = 0.f;
#pragma unroll
    for (int i = 0; i < 3; ++i) {
        const float c = v[i] - mu;
        s2 += c * c;
    }
    const float var = block_reduce_sum(s2, sm) * (1.0f / DIM);
    const float inv = rsqrtf(var + LN_EPS);
#pragma unroll
    for (int i = 0; i < 3; ++i) {
        const int d = t + i * 256;
        float o = (v[i] - mu) * inv * g[d] + beta[d];
        if (resid16 != nullptr) o += (float)resid16[(size_t)n * DIM + d];
        if (do_relu) o = fmaxf(o, 0.f);
        if (outf32 != nullptr) outf32[(size_t)n * DIM + d] = o;
        if (outf16 != nullptr) outf16[(size_t)n * DIM + d] = (f16)o;
    }
}

extern "C" void kernel_launch(void* const* d_in, const int* in_sizes, int n_in,
                              void* d_out, int out_size, void* d_ws, size_t ws_size,
                              hipStream_t stream) {
    const float* x      = (const float*)d_in[0];
    const int*   ei     = (const int*)d_in[1];
    const int*   et     = (const int*)d_in[2];
    const float* W_rel  = (const float*)d_in[3];
    const float* W_root = (const float*)d_in[4];
    const float* bias   = (const float*)d_in[5];
    const float* ln_g   = (const float*)d_in[6];
    const float* ln_b   = (const float*)d_in[7];
    float* out = (float*)d_out;

    // workspace carve-out
    char* w = (char*)d_ws;
    auto alloc = [&](size_t bytes) -> char* {
        char* p = w;
        w += (bytes + 255) & ~(size_t)255;
        return p;
    };
    f16* hf16      = (f16*)alloc((size_t)N_NODES * DIM * 2);
    f16* WT        = (f16*)alloc((size_t)(N_REL + 1) * W_ELEMS * 2);
    int* cnt       = (int*)alloc((size_t)N_NODES * N_REL * 4);
    int* deg       = (int*)alloc((size_t)N_NODES * 4);
    int* row_start = (int*)alloc((size_t)(N_NODES + 1) * 4);
    int* cursor    = (int*)alloc((size_t)N_NODES * 4);
    int* pack      = (int*)alloc((size_t)N_EDGES * 4);
    int* posmap    = (int*)alloc((size_t)N_REL * N_NODES * 4);
    int* mr        = (int*)alloc(64);
    int* zbase     = (int*)alloc(64);
    int* tile_rel  = (int*)alloc((size_t)GT_MAX * 4);
    int* srclist   = (int*)alloc((size_t)GT_MAX * 128 * 4);
    f16* Zg        = (f16*)w;  // remainder (~280 MB; compact Z needs ~226 MB)

    // ---- graph prep (layer-invariant, recomputed per call for determinism) ----
    hipMemsetAsync(cnt, 0, (size_t)N_NODES * N_REL * 4, stream);
    hipMemsetAsync(deg, 0, (size_t)N_NODES * 4, stream);
    hipMemsetAsync(mr, 0, 64, stream);
    hipMemsetAsync(posmap, 0xFF, (size_t)N_REL * N_NODES * 4, stream);  // -1
    hipMemsetAsync(tile_rel, 0xFF, (size_t)GT_MAX * 4, stream);         // -1
    hipMemsetAsync(srclist, 0, (size_t)GT_MAX * 128 * 4, stream);
    count_kernel<<<(N_EDGES + 255) / 256, 256, 0, stream>>>(ei, et, cnt, deg, posmap, mr);
    scan_kernel<<<1, 256, 0, stream>>>(deg, row_start, cursor);
    zprep_kernel<<<1, 64, 0, stream>>>(mr, zbase, tile_rel);
    fill_kernel<<<(N_EDGES + 255) / 256, 256, 0, stream>>>(ei, et, posmap, zbase, cursor,
                                                           pack, srclist);
    convx_kernel<<<(N_NODES * DIM / 4 + 255) / 256, 256, 0, stream>>>(x, hf16);

    const int mt = (N_NODES + 127) / 128;  // 235 root row-tiles
    for (int l = 0; l < N_LAYERS; ++l) {
        convw_kernel<<<dim3(24, 24, N_REL + 1), dim3(32, 8), 0, stream>>>(W_rel, W_root, WT, l);

        // root transform: agg (= d_out) = hf16 @ W_root, dense f32 write
        gemm_kernel<<<mt * 6, 256, 0, stream>>>(hf16, WT, nullptr, nullptr,
                                                (f16*)nullptr, out);
        // compact per-relation transform: Z[zrow] = hf16[srclist[zrow]] @ W_rel
        gemm_kernel<<<GT_MAX * 6, 256, 0, stream>>>(hf16, WT, srclist, tile_rel, Zg, nullptr);
        // aggregate: agg[dst] += sum Z[zrow]/cnt
        gather_kernel<<<N_NODES, 192, 0, stream>>>(Zg, row_start, pack, cnt, out);

        ln_kernel<<<N_NODES, 256, 0, stream>>>(
            out, bias + (size_t)l * DIM, ln_g + (size_t)l * DIM, ln_b + (size_t)l * DIM,
            (l > 0) ? hf16 : nullptr,
            (l == N_LAYERS - 1) ? out : nullptr,
            (l < N_LAYERS - 1) ? hf16 : nullptr,
            (l < N_LAYERS - 1) ? 1 : 0);
    }
}

// Round 7
// 1171.680 us; speedup vs baseline: 11.8619x; 1.3753x over previous
//
#include <hip/hip_runtime.h>

#define N_NODES 30000
#define N_EDGES 200000
#define DIM 768
#define N_REL 10
#define N_LAYERS 2
#define LN_EPS 1e-5f
#define W_ELEMS (DIM * DIM)
#define BKS 64            // GEMM k-step
#define GT_MAX 1573       // upper bound on compact row-tiles: ceil(E/128)+10

typedef _Float16 f16;
typedef _Float16 f16x4 __attribute__((ext_vector_type(4)));
typedef _Float16 f16x8 __attribute__((ext_vector_type(8)));
typedef float f32x4 __attribute__((ext_vector_type(4)));

#define GLD(gaddr, laddr)                                                              \
    __builtin_amdgcn_global_load_lds((const __attribute__((address_space(1))) void*)(gaddr), \
                                     (__attribute__((address_space(3))) void*)(laddr), 16, 0, 0)

// ---- count: cnt[dst][r], deg[dst]; mark (r,src) presence with plain store ----
__global__ void count_kernel(const int* __restrict__ ei, const int* __restrict__ et,
                             int* __restrict__ cnt, int* __restrict__ deg,
                             int* __restrict__ posmap) {
    int e = blockIdx.x * blockDim.x + threadIdx.x;
    if (e >= N_EDGES) return;
    int src = ei[e];
    int dst = ei[N_EDGES + e];
    int r = et[e];
    atomicAdd(&cnt[dst * N_REL + r], 1);
    atomicAdd(&deg[dst], 1);
    posmap[r * N_NODES + src] = 1;  // idempotent mark; no CAS, no shared counter
}

// ---- per-relation position scan: flags -> dense positions (src-ordered), mr[r] ----
#define PSCAN_CHUNK 118  // 256*118 >= N_NODES
__global__ void posscan_kernel(int* __restrict__ posmap, int* __restrict__ mr) {
    __shared__ int part[256];
    const int r = blockIdx.x;
    int* pm = posmap + (size_t)r * N_NODES;
    const int t = threadIdx.x;
    const int c0 = t * PSCAN_CHUNK;
    int s = 0;
    for (int i = 0; i < PSCAN_CHUNK; ++i) {
        const int idx = c0 + i;
        if (idx < N_NODES && pm[idx] == 1) ++s;
    }
    part[t] = s;
    __syncthreads();
    if (t == 0) {
        int a = 0;
        for (int i = 0; i < 256; ++i) { const int v = part[i]; part[i] = a; a += v; }
        mr[r] = a;
    }
    __syncthreads();
    int a = part[t];
    for (int i = 0; i < PSCAN_CHUNK; ++i) {
        const int idx = c0 + i;
        if (idx < N_NODES && pm[idx] == 1) pm[idx] = a++;
    }
}

// ---- single-block scan: row_start = exclusive prefix of deg; cursor = copy ----
#define SCAN_CHUNK 118  // 256*118 = 30208 >= N_NODES
__global__ void scan_kernel(const int* __restrict__ deg, int* __restrict__ row_start,
                            int* __restrict__ cursor) {
    __shared__ int part[256];
    __shared__ int off[257];
    const int t = threadIdx.x;
    const int c0 = t * SCAN_CHUNK;
    int s = 0;
    for (int i = 0; i < SCAN_CHUNK; ++i) {
        const int idx = c0 + i;
        if (idx < N_NODES) s += deg[idx];
    }
    part[t] = s;
    __syncthreads();
    if (t == 0) {
        int a = 0;
        for (int i = 0; i < 256; ++i) { off[i] = a; a += part[i]; }
        off[256] = a;
        row_start[N_NODES] = a;
    }
    __syncthreads();
    int a = off[t];
    for (int i = 0; i < SCAN_CHUNK; ++i) {
        const int idx = c0 + i;
        if (idx < N_NODES) {
            row_start[idx] = a;
            cursor[idx] = a;
            a += deg[idx];
        }
    }
}

// ---- zbase (128-aligned prefix of mr) + tile->rel table ----
__global__ void zprep_kernel(const int* __restrict__ mr, int* __restrict__ zbase,
                             int* __restrict__ tile_rel) {
    if (blockIdx.x == 0 && threadIdx.x == 0) {
        int zc = 0, tc = 0;
        for (int r = 0; r < N_REL; ++r) {
            zbase[r] = zc;
            const int nt = (mr[r] + 127) >> 7;
            for (int i = 0; i < nt; ++i) tile_rel[tc + i] = r;
            tc += nt;
            zc += nt << 7;
        }
    }
}

// ---- fill CSR: pack = (rel<<24) | zrow; srclist[zrow] = src ----
__global__ void fill_kernel(const int* __restrict__ ei, const int* __restrict__ et,
                            const int* __restrict__ posmap, const int* __restrict__ zbase,
                            int* __restrict__ cursor, int* __restrict__ pack,
                            int* __restrict__ srclist) {
    int e = blockIdx.x * blockDim.x + threadIdx.x;
    if (e >= N_EDGES) return;
    int src = ei[e];
    int dst = ei[N_EDGES + e];
    int r = et[e];
    const int zrow = zbase[r] + posmap[r * N_NODES + src];
    int pos = atomicAdd(&cursor[dst], 1);
    pack[pos] = (r << 24) | zrow;
    srclist[zrow] = src;  // idempotent (same value from all writers)
}

// ---- f32 -> f16 elementwise (x into hf16) ----
__global__ void convx_kernel(const float* __restrict__ in, f16* __restrict__ out) {
    int idx = blockIdx.x * blockDim.x + threadIdx.x;
    if (idx >= N_NODES * DIM / 4) return;
    const float4 v = *reinterpret_cast<const float4*>(in + (size_t)idx * 4);
    f16x4 o = {(f16)v.x, (f16)v.y, (f16)v.z, (f16)v.w};
    *reinterpret_cast<f16x4*>(out + (size_t)idx * 4) = o;
}

// ---- W convert + transpose: WT[s][j][k] = Wsrc[s][k][j] as f16 ----
__global__ void convw_kernel(const float* __restrict__ Wrel, const float* __restrict__ Wroot,
                             f16* __restrict__ WT, int layer) {
    __shared__ float tile[32][33];
    const int s = blockIdx.z;
    const float* src = (s < N_REL) ? (Wrel + ((size_t)layer * N_REL + s) * W_ELEMS)
                                   : (Wroot + (size_t)layer * W_ELEMS);
    const int k0 = blockIdx.x * 32;
    const int j0 = blockIdx.y * 32;
    const int tx = threadIdx.x;  // 0..31
    const int ty = threadIdx.y;  // 0..7
#pragma unroll
    for (int i = 0; i < 4; ++i)
        tile[ty + i * 8][tx] = src[(size_t)(k0 + ty + i * 8) * DIM + j0 + tx];
    __syncthreads();
    f16* dst = WT + (size_t)s * W_ELEMS;
#pragma unroll
    for (int i = 0; i < 4; ++i)
        dst[(size_t)(j0 + ty + i * 8) * DIM + k0 + tx] = (f16)tile[tx][ty + i * 8];
}

// ---- f16 MFMA GEMM, 2-phase dbuf, XCD-chunk-swizzled 1-D grid ----
// compact mode (tile_rel != null): A rows gathered via srclist, Z f16 out
// root mode    (tile_rel == null): dense rows, slab N_REL, f32 agg out
// LDS [128][BKS=64]: 16B k-chunks XOR-swizzled (chunk c holds global chunk
// c^(row&7)); linear GLD dest + pre-swizzled global src + swizzled ds_read.
__global__ void __launch_bounds__(256)
gemm_kernel(const f16* __restrict__ A, const f16* __restrict__ WT,
            const int* __restrict__ srclist, const int* __restrict__ tile_rel,
            f16* __restrict__ Zout, float* __restrict__ aggout) {
    __shared__ alignas(128) f16 As[2][128 * BKS];  // 2 x 16 KB
    __shared__ alignas(128) f16 Bs[2][128 * BKS];  // 2 x 16 KB

    // bijective XCD chunk swizzle (m204): consecutive work ids -> same XCD
    const int nwg = gridDim.x;
    const int orig = blockIdx.x;
    const int qq = nwg >> 3, rr = nwg & 7, xc = orig & 7, oo = orig >> 3;
    const int wg = (xc < rr ? xc * (qq + 1) : rr * (qq + 1) + (xc - rr) * qq) + oo;
    const int gt = wg / 6, jt = wg % 6;  // jt fast: one A-tile's n-blocks share an XCD

    int rel;
    if (tile_rel != nullptr) {
        rel = tile_rel[gt];
        if (rel < 0) return;  // uniform early-exit (past end of real tiles)
    } else {
        rel = N_REL;
    }

    const int t = threadIdx.x;
    const int wv = t >> 6, lane = t & 63;
    const int wr = wv >> 1, wc = wv & 1;
    const f16* B = WT + (size_t)rel * W_ELEMS + (size_t)(jt * 128) * DIM;

    // staging sources: chunk = q*256+t -> row chunk>>3, swizzled k-chunk
    const f16* gA[4];
    const f16* gB[4];
#pragma unroll
    for (int q = 0; q < 4; ++q) {
        const int chunk = q * 256 + t;
        const int row = chunk >> 3;
        const int gk = (chunk & 7) ^ (row & 7);
        int arow;
        if (tile_rel != nullptr) {
            arow = srclist[gt * 128 + row];
        } else {
            arow = gt * 128 + row;
            if (arow > N_NODES - 1) arow = N_NODES - 1;
        }
        gA[q] = A + (size_t)arow * DIM + gk * 8;
        gB[q] = B + (size_t)row * DIM + gk * 8;
    }

    f32x4 acc[4][4];
#pragma unroll
    for (int i = 0; i < 4; ++i)
#pragma unroll
        for (int j = 0; j < 4; ++j) acc[i][j] = (f32x4){0.f, 0.f, 0.f, 0.f};

    const int lr16 = lane & 15, lk = lane >> 4, l7 = lane & 7;

    // prologue: stage K-step 0 into buf 0
#pragma unroll
    for (int q = 0; q < 4; ++q) {
        GLD(gA[q], (char*)As[0] + q * 4096 + wv * 1024);
        GLD(gB[q], (char*)Bs[0] + q * 4096 + wv * 1024);
    }
    __syncthreads();

    for (int ks = 0; ks < DIM / BKS; ++ks) {
        const int cur = ks & 1;
        if (ks < DIM / BKS - 1) {  // issue next tile's stage BEFORE compute
#pragma unroll
            for (int q = 0; q < 4; ++q) {
                GLD(gA[q] + (ks + 1) * BKS, (char*)As[cur ^ 1] + q * 4096 + wv * 1024);
                GLD(gB[q] + (ks + 1) * BKS, (char*)Bs[cur ^ 1] + q * 4096 + wv * 1024);
            }
        }
#pragma unroll
        for (int h = 0; h < 2; ++h) {
            f16x8 a[4], b[4];
            const int cp = (((h << 2) | lk) ^ l7) * 8;  // swizzled k-chunk (f16 units)
#pragma unroll
            for (int i = 0; i < 4; ++i) {
                a[i] = *(const f16x8*)&As[cur][(wr * 64 + i * 16 + lr16) * BKS + cp];
                b[i] = *(const f16x8*)&Bs[cur][(wc * 64 + i * 16 + lr16) * BKS + cp];
            }
#pragma unroll
            for (int mi = 0; mi < 4; ++mi)
#pragma unroll
                for (int ni = 0; ni < 4; ++ni)
                    acc[mi][ni] =
                        __builtin_amdgcn_mfma_f32_16x16x32_f16(a[mi], b[ni], acc[mi][ni], 0, 0, 0);
        }
        __syncthreads();  // single barrier/K-step: drains next-tile stage after compute
    }

    const int lrow = lk * 4, lcol = lr16;
    const int c0 = jt * 128 + wc * 64;
    if (tile_rel != nullptr) {
#pragma unroll
        for (int mi = 0; mi < 4; ++mi)
#pragma unroll
            for (int q = 0; q < 4; ++q) {
                const int z = gt * 128 + wr * 64 + mi * 16 + lrow + q;  // padding rows ok
                f16* zp = Zout + (size_t)z * DIM + c0 + lcol;
#pragma unroll
                for (int ni = 0; ni < 4; ++ni) zp[ni * 16] = (f16)acc[mi][ni][q];
            }
    } else {
#pragma unroll
        for (int mi = 0; mi < 4; ++mi)
#pragma unroll
            for (int q = 0; q < 4; ++q) {
                const int row = gt * 128 + wr * 64 + mi * 16 + lrow + q;
                if (row >= N_NODES) continue;
                float* op = aggout + (size_t)row * DIM + c0 + lcol;
#pragma unroll
                for (int ni = 0; ni < 4; ++ni) op[ni * 16] = acc[mi][ni][q];
            }
    }
}

// ---- gather: agg[dst] += sum_e Z[zrow_e] / cnt[dst,rel_e]; no atomics ----
__global__ void __launch_bounds__(192)
gather_kernel(const f16* __restrict__ Z, const int* __restrict__ row_start,
              const int* __restrict__ pack, const int* __restrict__ cnt,
              float* __restrict__ agg) {
    const int dst = blockIdx.x;
    const int lo = row_start[dst];
    const int hi = row_start[dst + 1];
    if (lo == hi) return;
    const int t = threadIdx.x;  // 192 threads x 4 f16
    float a0 = 0.f, a1 = 0.f, a2 = 0.f, a3 = 0.f;
    for (int i = lo; i < hi; ++i) {
        const int p = pack[i];
        const int r = p >> 24;
        const int zrow = p & 0xFFFFFF;
        const float inv = 1.0f / (float)cnt[dst * N_REL + r];
        const f16x4 v = *reinterpret_cast<const f16x4*>(Z + (size_t)zrow * DIM + t * 4);
        a0 += (float)v[0] * inv;
        a1 += (float)v[1] * inv;
        a2 += (float)v[2] * inv;
        a3 += (float)v[3] * inv;
    }
    float* ap = agg + (size_t)dst * DIM + t * 4;
    float4 c = *reinterpret_cast<float4*>(ap);
    c.x += a0; c.y += a1; c.z += a2; c.w += a3;
    *reinterpret_cast<float4*>(ap) = c;
}

// ---- bias + LN + optional residual(f16) + optional relu; f32 and/or f16 out ----
__device__ __forceinline__ float block_reduce_sum(float v, float* sm) {
#pragma unroll
    for (int o = 32; o > 0; o >>= 1) v += __shfl_down(v, o, 64);
    const int wid = threadIdx.x >> 6;
    const int lane = threadIdx.x & 63;
    __syncthreads();
    if (lane == 0) sm[wid] = v;
    __syncthreads();
    return sm[0] + sm[1] + sm[2] + sm[3];
}

__global__ void __launch_bounds__(256)
ln_kernel(const float* __restrict__ agg, const float* __restrict__ bias,
          const float* __restrict__ g, const float* __restrict__ beta,
          const f16* __restrict__ resid16, float* __restrict__ outf32,
          f16* __restrict__ outf16, int do_relu) {
    __shared__ float sm[4];
    const int n = blockIdx.x;
    const int t = threadIdx.x;
    float v[3];
    float s = 0.f;
#pragma unroll
    for (int i = 0; i < 3; ++i) {
        const int d = t + i * 256;
        v[i] = agg[(size_t)n * DIM + d] + bias[d];
        s += v[i];
    }
    const float mu = block_reduce_sum(s, sm) * (1.0f / DIM);
    float s2 = 0.f;
#pragma unroll
    for (int i = 0; i < 3; ++i) {
        const float c = v[i] - mu;
        s2 += c * c;
    }
    const float var = block_reduce_sum(s2, sm) * (1.0f / DIM);
    const float inv = rsqrtf(var + LN_EPS);
#pragma unroll
    for (int i = 0; i < 3; ++i) {
        const int d = t + i * 256;
        float o = (v[i] - mu) * inv * g[d] + beta[d];
        if (resid16 != nullptr) o += (float)resid16[(size_t)n * DIM + d];
        if (do_relu) o = fmaxf(o, 0.f);
        if (outf32 != nullptr) outf32[(size_t)n * DIM + d] = o;
        if (outf16 != nullptr) outf16[(size_t)n * DIM + d] = (f16)o;
    }
}

extern "C" void kernel_launch(void* const* d_in, const int* in_sizes, int n_in,
                              void* d_out, int out_size, void* d_ws, size_t ws_size,
                              hipStream_t stream) {
    const float* x      = (const float*)d_in[0];
    const int*   ei     = (const int*)d_in[1];
    const int*   et     = (const int*)d_in[2];
    const float* W_rel  = (const float*)d_in[3];
    const float* W_root = (const float*)d_in[4];
    const float* bias   = (const float*)d_in[5];
    const float* ln_g   = (const float*)d_in[6];
    const float* ln_b   = (const float*)d_in[7];
    float* out = (float*)d_out;

    // workspace carve-out
    char* w = (char*)d_ws;
    auto alloc = [&](size_t bytes) -> char* {
        char* p = w;
        w += (bytes + 255) & ~(size_t)255;
        return p;
    };
    f16* hf16      = (f16*)alloc((size_t)N_NODES * DIM * 2);
    f16* WT        = (f16*)alloc((size_t)(N_REL + 1) * W_ELEMS * 2);
    int* cnt       = (int*)alloc((size_t)N_NODES * N_REL * 4);
    int* deg       = (int*)alloc((size_t)N_NODES * 4);
    int* row_start = (int*)alloc((size_t)(N_NODES + 1) * 4);
    int* cursor    = (int*)alloc((size_t)N_NODES * 4);
    int* pack      = (int*)alloc((size_t)N_EDGES * 4);
    int* posmap    = (int*)alloc((size_t)N_REL * N_NODES * 4);
    int* mr        = (int*)alloc(64);
    int* zbase     = (int*)alloc(64);
    int* tile_rel  = (int*)alloc((size_t)GT_MAX * 4);
    int* srclist   = (int*)alloc((size_t)GT_MAX * 128 * 4);
    f16* Zg        = (f16*)w;  // remainder (~280 MB; compact Z needs ~226 MB)

    // ---- graph prep (layer-invariant, recomputed per call for determinism) ----
    hipMemsetAsync(cnt, 0, (size_t)N_NODES * N_REL * 4, stream);
    hipMemsetAsync(deg, 0, (size_t)N_NODES * 4, stream);
    hipMemsetAsync(posmap, 0xFF, (size_t)N_REL * N_NODES * 4, stream);  // -1
    hipMemsetAsync(tile_rel, 0xFF, (size_t)GT_MAX * 4, stream);         // -1
    hipMemsetAsync(srclist, 0, (size_t)GT_MAX * 128 * 4, stream);
    count_kernel<<<(N_EDGES + 255) / 256, 256, 0, stream>>>(ei, et, cnt, deg, posmap);
    posscan_kernel<<<N_REL, 256, 0, stream>>>(posmap, mr);
    scan_kernel<<<1, 256, 0, stream>>>(deg, row_start, cursor);
    zprep_kernel<<<1, 64, 0, stream>>>(mr, zbase, tile_rel);
    fill_kernel<<<(N_EDGES + 255) / 256, 256, 0, stream>>>(ei, et, posmap, zbase, cursor,
                                                           pack, srclist);
    convx_kernel<<<(N_NODES * DIM / 4 + 255) / 256, 256, 0, stream>>>(x, hf16);

    const int mt = (N_NODES + 127) / 128;  // 235 root row-tiles
    for (int l = 0; l < N_LAYERS; ++l) {
        convw_kernel<<<dim3(24, 24, N_REL + 1), dim3(32, 8), 0, stream>>>(W_rel, W_root, WT, l);

        // root transform: agg (= d_out) = hf16 @ W_root, dense f32 write
        gemm_kernel<<<mt * 6, 256, 0, stream>>>(hf16, WT, nullptr, nullptr,
                                                (f16*)nullptr, out);
        // compact per-relation transform: Z[zrow] = hf16[srclist[zrow]] @ W_rel
        gemm_kernel<<<GT_MAX * 6, 256, 0, stream>>>(hf16, WT, srclist, tile_rel, Zg, nullptr);
        // aggregate: agg[dst] += sum Z[zrow]/cnt
        gather_kernel<<<N_NODES, 192, 0, stream>>>(Zg, row_start, pack, cnt, out);

        ln_kernel<<<N_NODES, 256, 0, stream>>>(
            out, bias + (size_t)l * DIM, ln_g + (size_t)l * DIM, ln_b + (size_t)l * DIM,
            (l > 0) ? hf16 : nullptr,
            (l == N_LAYERS - 1) ? out : nullptr,
            (l < N_LAYERS - 1) ? hf16 : nullptr,
            (l < N_LAYERS - 1) ? 1 : 0);
    }
}